// Round 1
// baseline (326.202 us; speedup 1.0000x reference)
//
#include <hip/hip_runtime.h>
#include <math.h>

#define NB_PER_BLOCK 8    // batches per 128-thread block (was 16/256: halved for 8 blocks/CU)
#define ROWSTRIDE 18      // A-row stride in LDS floats (16 data + 2 pad: 8B-aligned float2,
                          //  18*r mod 32 covers all 16 even bank residues -> min-cycle b64 access)
#define MATSTRIDE 578     // per-batch stride (32*18 + 2): keeps rows even-float-aligned, skews batches

// phase 1: 16 lanes/batch scan 128 occupancy ints -> sorted occupied-k lists
//          (slots 0..15: up k in [0,64); 16..31: dn k in [64,128)).
// phase 2: cooperative gather. 4 lanes own one (batch, A-row): each lane reads
//          ONE float4 (quarter row) per occupied k -> one dwordx4 per 64B line
//          touch (line-optimal: every fetched line fully consumed by the 4 lanes).
//          Accumulate over 32 k, write quarter-rows to LDS amat as 2x float2.
// phase 3: unchanged 8-lane LU with implicit partial pivoting (lexicographic
//          tie-break), rows read back from amat via float2. log|det| = sum
//          log|pivot|, sign parity = (#neg pivots + inversions) mod 2.
// occupancy: LDS 19.5KB/block -> 8 blocks/CU x 2 waves = 16 waves/CU (VGPR=68
//          caps at 4 waves/SIMD = 16/CU too). Was 43.5KB -> 3 blocks -> 12 waves.
// output:  planar complex: out[b] = re, out[B+b] = im.

__global__ __launch_bounds__(128, 4) void backflow_kernel(
    const int* __restrict__ nocc,   // (B,128) int32 0/1
    const float* __restrict__ W,    // (128,2048) f32 row-major
    float* __restrict__ out,        // planar: [B re][B im]
    int B)
{
    __shared__ int lists[NB_PER_BLOCK][33];
    __shared__ float amat[NB_PER_BLOCK * MATSTRIDE];   // 18,496 B

    const int tid = threadIdx.x;

    // ---------------- phase 1: occupancy -> k lists ----------------
    {
        const int bib1 = tid >> 4;                 // 0..7
        const int l16  = tid & 15;
        int batch1 = blockIdx.x * NB_PER_BLOCK + bib1;
        if (batch1 >= B) batch1 = B - 1;
        const int4* np = reinterpret_cast<const int4*>(nocc + (size_t)batch1 * 128 + l16 * 8);
        int4 v0 = np[0];
        int4 v1 = np[1];
        unsigned nib = 0;
        nib |= (v0.x != 0) ? 1u   : 0u;
        nib |= (v0.y != 0) ? 2u   : 0u;
        nib |= (v0.z != 0) ? 4u   : 0u;
        nib |= (v0.w != 0) ? 8u   : 0u;
        nib |= (v1.x != 0) ? 16u  : 0u;
        nib |= (v1.y != 0) ? 32u  : 0u;
        nib |= (v1.z != 0) ? 64u  : 0u;
        nib |= (v1.w != 0) ? 128u : 0u;
        const int cnt = __popc(nib);
        int incl = cnt;
        const int seg = l16 & 7;
        #pragma unroll
        for (int d = 1; d < 8; d <<= 1) {
            int t = __shfl_up(incl, d, 8);
            if (seg >= d) incl += t;
        }
        int pos = ((l16 >> 3) << 4) + (incl - cnt);
        const int k0 = l16 * 8;
        #pragma unroll
        for (int b = 0; b < 8; b++) {
            if (nib & (1u << b)) lists[bib1][pos++] = k0 + b;
        }
    }
    __syncthreads();

    // ---------------- phase 2: cooperative gather (4 lanes per A-row) ----------------
    {
        const int q = tid & 3;          // quarter within row
        const int G = tid >> 2;         // row-group 0..31
        #pragma unroll 1
        for (int p = 0; p < 8; p++) {
            const int rowflat = p * 32 + G;        // 0..255 = bib*32 + ridx
            const int bib2 = rowflat >> 5;
            const int ridx = rowflat & 31;         // 0..15 up, 16..31 dn
            const int m2 = ridx >> 4;
            const int r = lists[bib2][ridx] - (m2 << 6);
            const float* wp = W + r * 32 + m2 * 16 + q * 4;
            float4 acc = {0.f, 0.f, 0.f, 0.f};
            #pragma unroll 8
            for (int t = 0; t < 32; t++) {
                const int k = lists[bib2][t];
                const float4 v = *reinterpret_cast<const float4*>(wp + (size_t)k * 2048);
                acc.x += v.x; acc.y += v.y; acc.z += v.z; acc.w += v.w;
            }
            float* dst = &amat[bib2 * MATSTRIDE + ridx * ROWSTRIDE + q * 4];
            *reinterpret_cast<float2*>(dst)     = make_float2(acc.x, acc.y);
            *reinterpret_cast<float2*>(dst + 2) = make_float2(acc.z, acc.w);
        }
    }
    __syncthreads();

    // ---------------- phase 3: LU, implicit partial pivoting ----------------
    const int lane = tid & 63;
    const int wave = tid >> 6;          // 0..1
    const int g    = lane >> 3;         // matrix group in wave 0..7
    const int s8   = lane & 7;          // lane in group
    const int bw   = g >> 1;            // batch in wave 0..3
    const int m    = g & 1;             // 0 = up, 1 = dn
    const int bib  = (wave << 2) + bw;  // 0..7
    int batch = blockIdx.x * NB_PER_BLOCK + bib;
    const bool valid = (batch < B);
    if (batch >= B) batch = B - 1;

    float a0[16], a1[16];
    {
        const float* row0 = &amat[bib * MATSTRIDE + (m * 16 + s8) * ROWSTRIDE];
        const float* row1 = row0 + 8 * ROWSTRIDE;
        #pragma unroll
        for (int qq = 0; qq < 8; qq++) {
            float2 v0 = *reinterpret_cast<const float2*>(row0 + qq * 2);
            float2 v1 = *reinterpret_cast<const float2*>(row1 + qq * 2);
            a0[qq*2+0] = v0.x; a0[qq*2+1] = v0.y;
            a1[qq*2+0] = v1.x; a1[qq*2+1] = v1.y;
        }
    }

    unsigned active = 0xffffu;
    int inv = 0;
    float myd0 = 1.f, myd1 = 1.f;

    #pragma unroll
    for (int k = 0; k < 16; k++) {
        const unsigned act0 = (active >> s8) & 1u;
        const unsigned act1 = (active >> (s8 + 8)) & 1u;
        float av = act0 ? fabsf(a0[k]) : -1.f;
        int idx = s8;
        {
            float av1 = act1 ? fabsf(a1[k]) : -1.f;
            if (av1 > av) { av = av1; idx = s8 + 8; }
        }
        #pragma unroll
        for (int d = 1; d < 8; d <<= 1) {
            float ov = __shfl_xor(av, d, 8);
            int   oi = __shfl_xor(idx, d, 8);
            if (ov > av || (ov == av && oi < idx)) { av = ov; idx = oi; }
        }
        const int p = idx;
        const int plane = p & 7;
        const bool phi = (p & 8) != 0;
        float psel = phi ? a1[k] : a0[k];
        const float pk = __shfl(psel, plane, 8);
        const float rcp = 1.0f / pk;

        if (s8 == p)     myd0 = pk;
        if (s8 + 8 == p) myd1 = pk;
        inv += __popc(active & ((1u << p) - 1u));
        active &= ~(1u << p);

        const float f0 = (act0 && s8 != p)       ? a0[k] * rcp : 0.f;
        const float f1 = (act1 && (s8 + 8) != p) ? a1[k] * rcp : 0.f;

        #pragma unroll
        for (int j = k + 1; j < 16; j++) {
            float sel = phi ? a1[j] : a0[j];
            float pv = __shfl(sel, plane, 8);
            a0[j] = fmaf(-f0, pv, a0[j]);
            a1[j] = fmaf(-f1, pv, a1[j]);
        }
    }

    float ld = logf(fabsf(myd0)) + logf(fabsf(myd1));
    int ng = ((myd0 < 0.f) ? 1 : 0) + ((myd1 < 0.f) ? 1 : 0);
    #pragma unroll
    for (int d = 1; d < 8; d <<= 1) {
        ld += __shfl_xor(ld, d, 8);
        ng += __shfl_xor(ng, d, 8);
    }
    const int neg = (ng + inv) & 1;

    const float ld_o  = __shfl_xor(ld, 8, 16);
    const int   neg_o = __shfl_xor(neg, 8, 16);

    if ((lane & 15) == 0 && valid) {
        out[batch]     = ld + ld_o;                                      // re plane
        out[B + batch] = 3.14159265358979323846f * (float)(neg + neg_o); // im plane
    }
}

extern "C" void kernel_launch(void* const* d_in, const int* in_sizes, int n_in,
                              void* d_out, int out_size, void* d_ws, size_t ws_size,
                              hipStream_t stream) {
    const int* nocc = (const int*)d_in[0];
    const float* W  = (const float*)d_in[1];
    float* out = (float*)d_out;
    const int B = in_sizes[0] / 128;                      // 65536
    const int blocks = (B + NB_PER_BLOCK - 1) / NB_PER_BLOCK;  // 8192
    backflow_kernel<<<blocks, 128, 0, stream>>>(nocc, W, out, B);
}